// Round 1
// baseline (123.187 us; speedup 1.0000x reference)
//
#include <hip/hip_runtime.h>
#include <cmath>

#define BB 256
#define TT 16
#define SS 32
#define DD 768
#define LROW 260   // LDS staging row stride (floats), 16B-aligned

// ---------------------------------------------------------------------------
// wave-per-row LSE over cparts[p][3][256][256]; one atomicAdd per row.
// lane holds cols lane*4..lane*4+3 summed over the 8 K-partials.
// ---------------------------------------------------------------------------
__device__ __forceinline__ void wave_lse(
    const float* __restrict__ cparts, float* __restrict__ out,
    int cm, int row, float w)
{
    const int lane = threadIdx.x & 63;
    float4 x = make_float4(0.f, 0.f, 0.f, 0.f);
    const float* base = cparts + (size_t)cm * 65536 + (size_t)row * 256 + (lane << 2);
#pragma unroll
    for (int p = 0; p < 8; ++p) {
        float4 v = *(const float4*)(base + (size_t)p * 3 * 65536);
        x.x += v.x; x.y += v.y; x.z += v.z; x.w += v.w;
    }
    float m = fmaxf(fmaxf(x.x, x.y), fmaxf(x.z, x.w));
#pragma unroll
    for (int off = 32; off > 0; off >>= 1)
        m = fmaxf(m, __shfl_xor(m, off, 64));
    float e = expf(x.x - m) + expf(x.y - m) + expf(x.z - m) + expf(x.w - m);
#pragma unroll
    for (int off = 32; off > 0; off >>= 1)
        e += __shfl_xor(e, off, 64);
    if (lane == (row >> 2)) {
        float lse = m + logf(e);
        float xd = (row & 2) ? ((row & 1) ? x.w : x.z)
                             : ((row & 1) ? x.y : x.x);
        atomicAdd(out, w * (lse - xd));
    }
}

// ---------------------------------------------------------------------------
// K1: blocks 0..255  -> stage1 for batch row i (tw-weighted vw, tb mean)
//     blocks 256..383-> mat0 GEMM G = ls*vg@tg^T -> cparts cm=1 (+T into cm=2)
//     (mat0 GEMM is independent of stage1; 52KB LDS/block -> 2 blocks/CU so
//      it runs CONCURRENTLY with stage1 instead of serialized behind it)
// Both paths register-double-buffer the global->LDS staging: prefetch for
// chunk c+1 is issued AFTER the post-write barrier so the barrier's vmcnt
// drain doesn't kill the overlap; latency hides under the FMA phase.
// ---------------------------------------------------------------------------
__global__ __launch_bounds__(512, 4) void hl_k1(
    const float* __restrict__ vl, const float* __restrict__ tl,
    const float* __restrict__ vgp, const float* __restrict__ tgp,
    const float* __restrict__ temp,
    float* __restrict__ vw_ws, float* __restrict__ tb_ws,
    float* __restrict__ cparts, float* __restrict__ out, int out_n)
{
    __shared__ float lds[13024];   // union: stage1 staging / gemm As+Bs+Tb
    const int tid = threadIdx.x;
    const float lsc = expf(temp[0]);

    if (blockIdx.x < BB) {
        // ================= stage1 =================
        float* smem  = lds;           // [48][260]
        float* simb  = lds + 12480;   // [512]
        float* rmaxb = lds + 12992;   // [16]
        float* twb   = lds + 13008;   // [16]
        const int i = blockIdx.x;
        if (i == 0) {                 // replaces hipMemsetAsync dispatch
            for (int o = tid; o < out_n; o += 512) out[o] = 0.f;
        }

        const int slice = tid & 15;   // d sub-offset (16 lanes x 16B)
        const int g     = tid >> 4;
        const int tgr   = g >> 3;     // t rows tgr*4..+4
        const int sg    = g & 7;      // s rows sg*4..+4

        const float* vli = vl + (size_t)i * TT * DD;
        const float* tli = tl + (size_t)i * SS * DD;

        float acc[4][4];
#pragma unroll
        for (int a = 0; a < 4; ++a)
#pragma unroll
            for (int b = 0; b < 4; ++b) acc[a][b] = 0.f;

        float4 pre[6];
        // preload chunk 0 into registers
#pragma unroll
        for (int k = 0; k < 2; ++k) {
            int f4 = tid + (k << 9);
            pre[k] = *(const float4*)&vli[(f4 >> 6) * DD + ((f4 & 63) << 2)];
        }
#pragma unroll
        for (int k = 0; k < 4; ++k) {
            int f4 = tid + (k << 9);
            pre[2 + k] = *(const float4*)&tli[(f4 >> 6) * DD + ((f4 & 63) << 2)];
        }

        for (int c = 0; c < 3; ++c) {
            __syncthreads();          // readers of previous chunk done
#pragma unroll
            for (int k = 0; k < 2; ++k) {
                int f4 = tid + (k << 9);
                *(float4*)&smem[(f4 >> 6) * LROW + ((f4 & 63) << 2)] = pre[k];
            }
#pragma unroll
            for (int k = 0; k < 4; ++k) {
                int f4 = tid + (k << 9);
                *(float4*)&smem[(16 + (f4 >> 6)) * LROW + ((f4 & 63) << 2)] = pre[2 + k];
            }
            __syncthreads();          // staged chunk visible
            if (c < 2) {              // prefetch chunk c+1 (overlaps compute)
                const int d0n = (c + 1) << 8;
#pragma unroll
                for (int k = 0; k < 2; ++k) {
                    int f4 = tid + (k << 9);
                    pre[k] = *(const float4*)&vli[(f4 >> 6) * DD + d0n + ((f4 & 63) << 2)];
                }
#pragma unroll
                for (int k = 0; k < 4; ++k) {
                    int f4 = tid + (k << 9);
                    pre[2 + k] = *(const float4*)&tli[(f4 >> 6) * DD + d0n + ((f4 & 63) << 2)];
                }
            }
#pragma unroll
            for (int step = 0; step < 4; ++step) {
                const int db = (slice << 4) + (step << 2);
                float4 av[4], bv[4];
#pragma unroll
                for (int ti = 0; ti < 4; ++ti)
                    av[ti] = *(const float4*)&smem[(tgr * 4 + ti) * LROW + db];
#pragma unroll
                for (int sj = 0; sj < 4; ++sj)
                    bv[sj] = *(const float4*)&smem[(16 + sg * 4 + sj) * LROW + db];
#pragma unroll
                for (int ti = 0; ti < 4; ++ti)
#pragma unroll
                    for (int sj = 0; sj < 4; ++sj)
                        acc[ti][sj] += av[ti].x * bv[sj].x + av[ti].y * bv[sj].y
                                     + av[ti].z * bv[sj].z + av[ti].w * bv[sj].w;
            }
        }
        __syncthreads();              // all reads of staging done before reuse

        // split-D transpose (alias staging region): [pair][slice], pad 17
#pragma unroll
        for (int ti = 0; ti < 4; ++ti)
#pragma unroll
            for (int sj = 0; sj < 4; ++sj) {
                int t = tgr * 4 + ti, s = sg * 4 + sj;
                smem[(t * 32 + s) * 17 + slice] = acc[ti][sj];
            }
        __syncthreads();
        {   // pair `tid` reduce over 16 slices
            float ssum = 0.f;
#pragma unroll
            for (int k = 0; k < 16; ++k) ssum += smem[tid * 17 + k];
            simb[tid] = lsc * ssum;
        }
        __syncthreads();
        if (tid < 16) {               // rowmax over s (rotated to avoid clash)
            float m = -3.0e38f;
            for (int s = 0; s < 32; ++s)
                m = fmaxf(m, simb[tid * 32 + ((s + tid) & 31)]);
            rmaxb[tid] = m;
        }
        __syncthreads();
        if (tid == 0) {               // tw = softmax over 16 t values
            float M = -3.0e38f;
            for (int t = 0; t < 16; ++t) M = fmaxf(M, rmaxb[t]);
            float ssum = 0.f;
            for (int t = 0; t < 16; ++t) {
                float e = expf(rmaxb[t] - M);
                twb[t] = e;
                ssum += e;
            }
            float inv = 1.0f / ssum;
            for (int t = 0; t < 16; ++t) twb[t] *= inv;
        }
        __syncthreads();

        // vw / tb tails: coalesced, L2-hot re-read
        for (int d = tid; d < DD; d += 512) {
            float vwv = 0.f;
#pragma unroll
            for (int t = 0; t < 16; ++t) vwv += twb[t] * vli[t * DD + d];
            vw_ws[(size_t)i * DD + d] = vwv;
            float tbv = 0.f;
#pragma unroll
            for (int s = 0; s < 32; ++s) tbv += tli[s * DD + d];
            tb_ws[(size_t)i * DD + d] = tbv * (1.0f / 32.0f);
        }
    } else {
        // ================= mat0 GEMM (256 active threads) =================
        float (*As)[68] = (float (*)[68])lds;
        float (*Bs)[68] = (float (*)[68])(lds + 1088);
        float (*Tb)[68] = (float (*)[68])(lds + 2176);
        const int b  = blockIdx.x - BB;
        const int p  = b & 7;
        const int tj = (b >> 3) & 3;
        const int ti = b >> 5;
        const int i0 = ti * 64, j0 = tj * 64, kb0 = p * 96;
        const bool act = tid < 256;
        const int srow = tid >> 2, skq = tid & 3;
        const int tr = tid >> 4, tc = tid & 15;

        float acc[4][4];
#pragma unroll
        for (int r = 0; r < 4; ++r)
#pragma unroll
            for (int cc = 0; cc < 4; ++cc) acc[r][cc] = 0.f;

        float4 a4 = make_float4(0.f, 0.f, 0.f, 0.f), b4 = a4;
        float4 a4n = a4, b4n = b4;
        if (act) {
            a4 = *(const float4*)&vgp[(size_t)(i0 + srow) * DD + kb0 + skq * 4];
            b4 = *(const float4*)&tgp[(size_t)(j0 + srow) * DD + kb0 + skq * 4];
        }
        for (int ch = 0; ch < 6; ++ch) {
            __syncthreads();
            if (act) {
                As[skq * 4 + 0][srow] = a4.x; As[skq * 4 + 1][srow] = a4.y;
                As[skq * 4 + 2][srow] = a4.z; As[skq * 4 + 3][srow] = a4.w;
                Bs[skq * 4 + 0][srow] = b4.x; Bs[skq * 4 + 1][srow] = b4.y;
                Bs[skq * 4 + 2][srow] = b4.z; Bs[skq * 4 + 3][srow] = b4.w;
            }
            __syncthreads();
            if (act && ch < 5) {      // prefetch next K-chunk under compute
                const int kb = kb0 + (ch + 1) * 16;
                a4n = *(const float4*)&vgp[(size_t)(i0 + srow) * DD + kb + skq * 4];
                b4n = *(const float4*)&tgp[(size_t)(j0 + srow) * DD + kb + skq * 4];
            }
            if (act) {
#pragma unroll
                for (int k = 0; k < 16; ++k) {
                    float4 av = *(const float4*)&As[k][tr * 4];
                    float4 bv = *(const float4*)&Bs[k][tc * 4];
                    float ar[4] = {av.x, av.y, av.z, av.w};
                    float br[4] = {bv.x, bv.y, bv.z, bv.w};
#pragma unroll
                    for (int r = 0; r < 4; ++r)
#pragma unroll
                        for (int cc = 0; cc < 4; ++cc)
                            acc[r][cc] += ar[r] * br[cc];
                }
            }
            a4 = a4n; b4 = b4n;
        }

        if (act) {
            float* Cp = cparts + ((size_t)p * 3 + 1) * 65536;
#pragma unroll
            for (int r = 0; r < 4; ++r) {
                float4 v = {acc[r][0] * lsc, acc[r][1] * lsc,
                            acc[r][2] * lsc, acc[r][3] * lsc};
                *(float4*)&Cp[(size_t)(i0 + tr * 4 + r) * 256 + j0 + tc * 4] = v;
            }
        }
        __syncthreads();
        if (act) {
#pragma unroll
            for (int r = 0; r < 4; ++r)
#pragma unroll
                for (int cc = 0; cc < 4; ++cc)
                    Tb[tc * 4 + cc][tr * 4 + r] = acc[r][cc] * lsc;
        }
        __syncthreads();
        if (act) {
            float* Ct = cparts + ((size_t)p * 3 + 2) * 65536;
#pragma unroll
            for (int r = 0; r < 4; ++r) {
                float4 v = *(const float4*)&Tb[tr * 4 + r][tc * 4];
                *(float4*)&Ct[(size_t)(j0 + tr * 4 + r) * 256 + i0 + tc * 4] = v;
            }
        }
    }
}

// ---------------------------------------------------------------------------
// K2: blocks 0..127  -> mat1 GEMM L = ls*vw@tb^T -> cparts cm=0
//     blocks 128..255-> LSE for the two GLOBAL losses (cm=1 rows, cm=2 rows),
//                       which depend only on K1 -> overlap with the GEMM.
// ---------------------------------------------------------------------------
__global__ __launch_bounds__(256) void hl_k2(
    const float* __restrict__ vw, const float* __restrict__ tbm,
    const float* __restrict__ temp, float* __restrict__ cparts,
    float* __restrict__ out)
{
    const int tid = threadIdx.x;
    const int b   = blockIdx.x;
    if (b < 128) {
        __shared__ float As[16][68];
        __shared__ float Bs[16][68];
        const float lsc = expf(temp[0]);
        const int p = b & 7, tj = (b >> 3) & 3, ti = b >> 5;
        const int i0 = ti * 64, j0 = tj * 64, kb0 = p * 96;
        const int srow = tid >> 2, skq = tid & 3;
        const int tr = tid >> 4, tc = tid & 15;

        float acc[4][4];
#pragma unroll
        for (int r = 0; r < 4; ++r)
#pragma unroll
            for (int cc = 0; cc < 4; ++cc) acc[r][cc] = 0.f;

        float4 a4 = *(const float4*)&vw [(size_t)(i0 + srow) * DD + kb0 + skq * 4];
        float4 b4 = *(const float4*)&tbm[(size_t)(j0 + srow) * DD + kb0 + skq * 4];
        float4 a4n = a4, b4n = b4;
        for (int ch = 0; ch < 6; ++ch) {
            __syncthreads();
            As[skq * 4 + 0][srow] = a4.x; As[skq * 4 + 1][srow] = a4.y;
            As[skq * 4 + 2][srow] = a4.z; As[skq * 4 + 3][srow] = a4.w;
            Bs[skq * 4 + 0][srow] = b4.x; Bs[skq * 4 + 1][srow] = b4.y;
            Bs[skq * 4 + 2][srow] = b4.z; Bs[skq * 4 + 3][srow] = b4.w;
            __syncthreads();
            if (ch < 5) {             // prefetch next K-chunk under compute
                const int kb = kb0 + (ch + 1) * 16;
                a4n = *(const float4*)&vw [(size_t)(i0 + srow) * DD + kb + skq * 4];
                b4n = *(const float4*)&tbm[(size_t)(j0 + srow) * DD + kb + skq * 4];
            }
#pragma unroll
            for (int k = 0; k < 16; ++k) {
                float4 av = *(const float4*)&As[k][tr * 4];
                float4 bv = *(const float4*)&Bs[k][tc * 4];
                float ar[4] = {av.x, av.y, av.z, av.w};
                float br[4] = {bv.x, bv.y, bv.z, bv.w};
#pragma unroll
                for (int r = 0; r < 4; ++r)
#pragma unroll
                    for (int cc = 0; cc < 4; ++cc)
                        acc[r][cc] += ar[r] * br[cc];
            }
            a4 = a4n; b4 = b4n;
        }

        float* Cp = cparts + (size_t)p * 3 * 65536;   // cm = 0
#pragma unroll
        for (int r = 0; r < 4; ++r) {
            float4 v = {acc[r][0] * lsc, acc[r][1] * lsc,
                        acc[r][2] * lsc, acc[r][3] * lsc};
            *(float4*)&Cp[(size_t)(i0 + tr * 4 + r) * 256 + j0 + tc * 4] = v;
        }
    } else {
        const int idx = b - 128;              // 0..127 -> 512 rows (cm=1,2)
        const int cm  = 1 + (idx >> 6);
        const int row = ((idx & 63) << 2) + (tid >> 6);
        wave_lse(cparts, out, cm, row, 0.3f / 256.0f);
    }
}

// ---------------------------------------------------------------------------
// K3: local-loss LSE (cm=0), 64 blocks x 4 waves = 256 rows.
// ---------------------------------------------------------------------------
__global__ __launch_bounds__(256) void hl_k3(
    const float* __restrict__ cparts, float* __restrict__ out)
{
    const int row = (blockIdx.x << 2) + (threadIdx.x >> 6);
    wave_lse(cparts, out, 0, row, 0.4f / 256.0f);
}

extern "C" void kernel_launch(void* const* d_in, const int* in_sizes, int n_in,
                              void* d_out, int out_size, void* d_ws, size_t ws_size,
                              hipStream_t stream)
{
    const float* vg   = (const float*)d_in[0];  // [256,768]
    const float* tg   = (const float*)d_in[1];  // [256,768]
    const float* vl   = (const float*)d_in[2];  // [256,16,768]
    const float* tl   = (const float*)d_in[3];  // [256,32,768]
    const float* temp = (const float*)d_in[4];  // [1]
    float* out = (float*)d_out;

    float* vw     = (float*)d_ws;                   // [256,768]
    float* tbw    = vw + (size_t)BB * DD;           // [256,768]
    float* cparts = tbw + (size_t)BB * DD;          // [8][3][256][256]

    hl_k1<<<dim3(BB + 128), dim3(512), 0, stream>>>(vl, tl, vg, tg, temp,
                                                    vw, tbw, cparts, out, out_size);
    hl_k2<<<dim3(256), dim3(256), 0, stream>>>(vw, tbw, temp, cparts, out);
    hl_k3<<<dim3(64),  dim3(256), 0, stream>>>(cparts, out);
}

// Round 2
// 120.910 us; speedup vs baseline: 1.0188x; 1.0188x over previous
//
#include <hip/hip_runtime.h>
#include <cmath>

#define BB 256
#define TT 16
#define SS 32
#define DD 768
#define LROW 260   // LDS staging row stride (floats), 16B-aligned

// ---------------------------------------------------------------------------
// wave-per-row LSE over cparts[p][3][256][256]; one atomicAdd per row.
// lane holds cols lane*4..lane*4+3 summed over the 8 K-partials.
// ---------------------------------------------------------------------------
__device__ __forceinline__ void wave_lse(
    const float* __restrict__ cparts, float* __restrict__ out,
    int cm, int row, float w)
{
    const int lane = threadIdx.x & 63;
    float4 x = make_float4(0.f, 0.f, 0.f, 0.f);
    const float* base = cparts + (size_t)cm * 65536 + (size_t)row * 256 + (lane << 2);
#pragma unroll
    for (int p = 0; p < 8; ++p) {
        float4 v = *(const float4*)(base + (size_t)p * 3 * 65536);
        x.x += v.x; x.y += v.y; x.z += v.z; x.w += v.w;
    }
    float m = fmaxf(fmaxf(x.x, x.y), fmaxf(x.z, x.w));
#pragma unroll
    for (int off = 32; off > 0; off >>= 1)
        m = fmaxf(m, __shfl_xor(m, off, 64));
    float e = expf(x.x - m) + expf(x.y - m) + expf(x.z - m) + expf(x.w - m);
#pragma unroll
    for (int off = 32; off > 0; off >>= 1)
        e += __shfl_xor(e, off, 64);
    if (lane == (row >> 2)) {
        float lse = m + logf(e);
        float xd = (row & 2) ? ((row & 1) ? x.w : x.z)
                             : ((row & 1) ? x.y : x.x);
        atomicAdd(out, w * (lse - xd));
    }
}

// ---------------------------------------------------------------------------
// K1: blocks 0..255   -> stage1 (EXACT baseline internals) for batch row i
//     blocks 256..319 -> mat0 GEMM G = ls*vg@tg^T, TWO 64x64 tile-jobs per
//                        block (one per 256-thread half, symmetric barriers)
//                        -> cparts cm=1 (+ transpose into cm=2)
// No launch-bounds min-waves clause: do not constrain the register allocator.
// ---------------------------------------------------------------------------
__global__ __launch_bounds__(512) void hl_k1(
    const float* __restrict__ vl, const float* __restrict__ tl,
    const float* __restrict__ vgp, const float* __restrict__ tgp,
    const float* __restrict__ temp,
    float* __restrict__ vw_ws, float* __restrict__ tb_ws,
    float* __restrict__ cparts, float* __restrict__ out, int out_n)
{
    __shared__ float lds[13056];   // union: stage1 (13024) / 2x gemm (2x6528)
    const int tid = threadIdx.x;
    const float lsc = expf(temp[0]);

    if (blockIdx.x < BB) {
        // ================= stage1 (baseline-verbatim internals) ============
        float* smem  = lds;           // [48][260]
        float* simb  = lds + 12480;   // [512]
        float* rmaxb = lds + 12992;   // [16]
        float* twb   = lds + 13008;   // [16]
        const int i = blockIdx.x;
        if (i == 0) {                 // replaces hipMemsetAsync dispatch
            for (int o = tid; o < out_n; o += 512) out[o] = 0.f;
        }

        const int slice = tid & 15;   // d sub-offset (16 lanes x 16B)
        const int g     = tid >> 4;
        const int tgr   = g >> 3;     // t rows tgr*4..+4
        const int sg    = g & 7;      // s rows sg*4..+4

        const float* vli = vl + (size_t)i * TT * DD;
        const float* tli = tl + (size_t)i * SS * DD;

        float acc[4][4];
#pragma unroll
        for (int a = 0; a < 4; ++a)
#pragma unroll
            for (int b = 0; b < 4; ++b) acc[a][b] = 0.f;

        for (int c = 0; c < 3; ++c) {
            const int d0 = c << 8;
#pragma unroll
            for (int k = 0; k < 2; ++k) {
                int f4 = tid + (k << 9);
                int r  = f4 >> 6;
                int dc = (f4 & 63) << 2;
                *(float4*)&smem[r * LROW + dc] = *(const float4*)&vli[r * DD + d0 + dc];
            }
#pragma unroll
            for (int k = 0; k < 4; ++k) {
                int f4 = tid + (k << 9);
                int r  = f4 >> 6;
                int dc = (f4 & 63) << 2;
                *(float4*)&smem[(16 + r) * LROW + dc] = *(const float4*)&tli[r * DD + d0 + dc];
            }
            __syncthreads();
#pragma unroll
            for (int step = 0; step < 4; ++step) {
                const int db = (slice << 4) + (step << 2);
                float4 av[4], bv[4];
#pragma unroll
                for (int ti = 0; ti < 4; ++ti)
                    av[ti] = *(const float4*)&smem[(tgr * 4 + ti) * LROW + db];
#pragma unroll
                for (int sj = 0; sj < 4; ++sj)
                    bv[sj] = *(const float4*)&smem[(16 + sg * 4 + sj) * LROW + db];
#pragma unroll
                for (int ti = 0; ti < 4; ++ti)
#pragma unroll
                    for (int sj = 0; sj < 4; ++sj)
                        acc[ti][sj] += av[ti].x * bv[sj].x + av[ti].y * bv[sj].y
                                     + av[ti].z * bv[sj].z + av[ti].w * bv[sj].w;
            }
            __syncthreads();
        }

        // split-D transpose (alias staging region): [pair][slice], pad 17
#pragma unroll
        for (int ti = 0; ti < 4; ++ti)
#pragma unroll
            for (int sj = 0; sj < 4; ++sj) {
                int t = tgr * 4 + ti, s = sg * 4 + sj;
                smem[(t * 32 + s) * 17 + slice] = acc[ti][sj];
            }
        __syncthreads();
        {   // pair `tid` reduce over 16 slices
            float ssum = 0.f;
#pragma unroll
            for (int k = 0; k < 16; ++k) ssum += smem[tid * 17 + k];
            simb[tid] = lsc * ssum;
        }
        __syncthreads();
        if (tid < 16) {               // rowmax over s (rotated to avoid clash)
            float m = -3.0e38f;
            for (int s = 0; s < 32; ++s)
                m = fmaxf(m, simb[tid * 32 + ((s + tid) & 31)]);
            rmaxb[tid] = m;
        }
        __syncthreads();
        if (tid == 0) {               // tw = softmax over 16 t values
            float M = -3.0e38f;
            for (int t = 0; t < 16; ++t) M = fmaxf(M, rmaxb[t]);
            float ssum = 0.f;
            for (int t = 0; t < 16; ++t) {
                float e = expf(rmaxb[t] - M);
                twb[t] = e;
                ssum += e;
            }
            float inv = 1.0f / ssum;
            for (int t = 0; t < 16; ++t) twb[t] *= inv;
        }
        __syncthreads();

        // vw / tb tails: coalesced, L2-hot re-read
        for (int d = tid; d < DD; d += 512) {
            float vwv = 0.f;
#pragma unroll
            for (int t = 0; t < 16; ++t) vwv += twb[t] * vli[t * DD + d];
            vw_ws[(size_t)i * DD + d] = vwv;
            float tbv = 0.f;
#pragma unroll
            for (int s = 0; s < 32; ++s) tbv += tli[s * DD + d];
            tb_ws[(size_t)i * DD + d] = tbv * (1.0f / 32.0f);
        }
    } else {
        // ========== mat0 GEMM: two jobs per block, all lanes active ========
        const int h   = tid >> 8;                 // half 0/1
        const int t   = tid & 255;
        const int job = ((blockIdx.x - BB) << 1) | h;   // 0..127
        float* base = lds + h * 6528;
        float (*As)[68] = (float (*)[68])base;
        float (*Bs)[68] = (float (*)[68])(base + 1088);
        float (*Tb)[68] = (float (*)[68])(base + 2176);  // 64x68

        const int p  = job & 7;
        const int tj = (job >> 3) & 3;
        const int ti = job >> 5;
        const int i0 = ti * 64, j0 = tj * 64, kb0 = p * 96;
        const int srow = t >> 2, skq = t & 3;
        const int tr = t >> 4, tc = t & 15;

        float acc[4][4];
#pragma unroll
        for (int r = 0; r < 4; ++r)
#pragma unroll
            for (int cc = 0; cc < 4; ++cc) acc[r][cc] = 0.f;

        float4 a4 = *(const float4*)&vgp[(size_t)(i0 + srow) * DD + kb0 + skq * 4];
        float4 b4 = *(const float4*)&tgp[(size_t)(j0 + srow) * DD + kb0 + skq * 4];
        float4 a4n = a4, b4n = b4;
        for (int ch = 0; ch < 6; ++ch) {
            __syncthreads();
            As[skq * 4 + 0][srow] = a4.x; As[skq * 4 + 1][srow] = a4.y;
            As[skq * 4 + 2][srow] = a4.z; As[skq * 4 + 3][srow] = a4.w;
            Bs[skq * 4 + 0][srow] = b4.x; Bs[skq * 4 + 1][srow] = b4.y;
            Bs[skq * 4 + 2][srow] = b4.z; Bs[skq * 4 + 3][srow] = b4.w;
            __syncthreads();
            if (ch < 5) {             // prefetch next K-chunk under compute
                const int kb = kb0 + (ch + 1) * 16;
                a4n = *(const float4*)&vgp[(size_t)(i0 + srow) * DD + kb + skq * 4];
                b4n = *(const float4*)&tgp[(size_t)(j0 + srow) * DD + kb + skq * 4];
            }
#pragma unroll
            for (int k = 0; k < 16; ++k) {
                float4 av = *(const float4*)&As[k][tr * 4];
                float4 bv = *(const float4*)&Bs[k][tc * 4];
                float ar[4] = {av.x, av.y, av.z, av.w};
                float br[4] = {bv.x, bv.y, bv.z, bv.w};
#pragma unroll
                for (int r = 0; r < 4; ++r)
#pragma unroll
                    for (int cc = 0; cc < 4; ++cc)
                        acc[r][cc] += ar[r] * br[cc];
            }
            a4 = a4n; b4 = b4n;
        }

        float* Cp = cparts + ((size_t)p * 3 + 1) * 65536;
#pragma unroll
        for (int r = 0; r < 4; ++r) {
            float4 v = {acc[r][0] * lsc, acc[r][1] * lsc,
                        acc[r][2] * lsc, acc[r][3] * lsc};
            *(float4*)&Cp[(size_t)(i0 + tr * 4 + r) * 256 + j0 + tc * 4] = v;
        }
        __syncthreads();
#pragma unroll
        for (int r = 0; r < 4; ++r)
#pragma unroll
            for (int cc = 0; cc < 4; ++cc)
                Tb[tc * 4 + cc][tr * 4 + r] = acc[r][cc] * lsc;
        __syncthreads();
        float* Ct = cparts + ((size_t)p * 3 + 2) * 65536;
#pragma unroll
        for (int r = 0; r < 4; ++r) {
            float4 v = *(const float4*)&Tb[tr * 4 + r][tc * 4];
            *(float4*)&Ct[(size_t)(j0 + tr * 4 + r) * 256 + i0 + tc * 4] = v;
        }
    }
}

// ---------------------------------------------------------------------------
// K2: blocks 0..63   -> mat1 GEMM L = ls*vw@tb^T (two jobs/block) -> cm=0
//     blocks 64..127 -> global LSEs (cm=1 rows = v2t, cm=2 rows = t2v),
//                       8 rows per block (one per wave); depends only on K1
//                       so it overlaps the GEMM.
// ---------------------------------------------------------------------------
__global__ __launch_bounds__(512) void hl_k2(
    const float* __restrict__ vw, const float* __restrict__ tbm,
    const float* __restrict__ temp, float* __restrict__ cparts,
    float* __restrict__ out)
{
    __shared__ float lds2[4352];      // 2x (As 1088 + Bs 1088)
    const int tid = threadIdx.x;
    if (blockIdx.x < 64) {
        const float lsc = expf(temp[0]);
        const int h   = tid >> 8;
        const int t   = tid & 255;
        const int job = (blockIdx.x << 1) | h;   // 0..127
        float* base = lds2 + h * 2176;
        float (*As)[68] = (float (*)[68])base;
        float (*Bs)[68] = (float (*)[68])(base + 1088);

        const int p  = job & 7;
        const int tj = (job >> 3) & 3;
        const int ti = job >> 5;
        const int i0 = ti * 64, j0 = tj * 64, kb0 = p * 96;
        const int srow = t >> 2, skq = t & 3;
        const int tr = t >> 4, tc = t & 15;

        float acc[4][4];
#pragma unroll
        for (int r = 0; r < 4; ++r)
#pragma unroll
            for (int cc = 0; cc < 4; ++cc) acc[r][cc] = 0.f;

        float4 a4 = *(const float4*)&vw [(size_t)(i0 + srow) * DD + kb0 + skq * 4];
        float4 b4 = *(const float4*)&tbm[(size_t)(j0 + srow) * DD + kb0 + skq * 4];
        float4 a4n = a4, b4n = b4;
        for (int ch = 0; ch < 6; ++ch) {
            __syncthreads();
            As[skq * 4 + 0][srow] = a4.x; As[skq * 4 + 1][srow] = a4.y;
            As[skq * 4 + 2][srow] = a4.z; As[skq * 4 + 3][srow] = a4.w;
            Bs[skq * 4 + 0][srow] = b4.x; Bs[skq * 4 + 1][srow] = b4.y;
            Bs[skq * 4 + 2][srow] = b4.z; Bs[skq * 4 + 3][srow] = b4.w;
            __syncthreads();
            if (ch < 5) {             // prefetch next K-chunk under compute
                const int kb = kb0 + (ch + 1) * 16;
                a4n = *(const float4*)&vw [(size_t)(i0 + srow) * DD + kb + skq * 4];
                b4n = *(const float4*)&tbm[(size_t)(j0 + srow) * DD + kb + skq * 4];
            }
#pragma unroll
            for (int k = 0; k < 16; ++k) {
                float4 av = *(const float4*)&As[k][tr * 4];
                float4 bv = *(const float4*)&Bs[k][tc * 4];
                float ar[4] = {av.x, av.y, av.z, av.w};
                float br[4] = {bv.x, bv.y, bv.z, bv.w};
#pragma unroll
                for (int r = 0; r < 4; ++r)
#pragma unroll
                    for (int cc = 0; cc < 4; ++cc)
                        acc[r][cc] += ar[r] * br[cc];
            }
            a4 = a4n; b4 = b4n;
        }

        float* Cp = cparts + (size_t)p * 3 * 65536;   // cm = 0
#pragma unroll
        for (int r = 0; r < 4; ++r) {
            float4 v = {acc[r][0] * lsc, acc[r][1] * lsc,
                        acc[r][2] * lsc, acc[r][3] * lsc};
            *(float4*)&Cp[(size_t)(i0 + tr * 4 + r) * 256 + j0 + tc * 4] = v;
        }
    } else {
        const int rr  = ((blockIdx.x - 64) << 3) + (tid >> 6);  // 0..511
        const int cm  = 1 + (rr >> 8);
        const int row = rr & 255;
        wave_lse(cparts, out, cm, row, 0.3f / 256.0f);
    }
}

// ---------------------------------------------------------------------------
// K3: local-loss LSE (cm=0), 32 blocks x 8 waves = 256 rows.
// ---------------------------------------------------------------------------
__global__ __launch_bounds__(512) void hl_k3(
    const float* __restrict__ cparts, float* __restrict__ out)
{
    const int row = (blockIdx.x << 3) + (threadIdx.x >> 6);
    wave_lse(cparts, out, 0, row, 0.4f / 256.0f);
}

extern "C" void kernel_launch(void* const* d_in, const int* in_sizes, int n_in,
                              void* d_out, int out_size, void* d_ws, size_t ws_size,
                              hipStream_t stream)
{
    const float* vg   = (const float*)d_in[0];  // [256,768]
    const float* tg   = (const float*)d_in[1];  // [256,768]
    const float* vl   = (const float*)d_in[2];  // [256,16,768]
    const float* tl   = (const float*)d_in[3];  // [256,32,768]
    const float* temp = (const float*)d_in[4];  // [1]
    float* out = (float*)d_out;

    float* vw     = (float*)d_ws;                   // [256,768]
    float* tbw    = vw + (size_t)BB * DD;           // [256,768]
    float* cparts = tbw + (size_t)BB * DD;          // [8][3][256][256]

    hl_k1<<<dim3(BB + 64), dim3(512), 0, stream>>>(vl, tl, vg, tg, temp,
                                                   vw, tbw, cparts, out, out_size);
    hl_k2<<<dim3(128), dim3(512), 0, stream>>>(vw, tbw, temp, cparts, out);
    hl_k3<<<dim3(32),  dim3(512), 0, stream>>>(cparts, out);
}